// Round 12
// baseline (28.989 us; speedup 1.0000x reference)
//
#include <hip/hip_runtime.h>
#include <hip/hip_fp16.h>

// Problem constants (from reference)
#define BSZ     1024   // batch
#define N_IN    1024
#define NLAYERS 5
#define NPL     2048   // nodes per layer
#define FANIN   16
#define N_OUT   256

#define VALS_ROWS   (N_IN + 4 * NPL)            // 9216 gatherable rows
#define CPB         4                           // batch columns per block
#define NBLK        (BSZ / CPB)                 // 256 blocks
#define ROW_B       8                           // 4 cols x fp16 per row
#define LDS_BYTES   (VALS_ROWS * ROW_B)         // 73728 B

union H4 { unsigned long long u; __half2 h2[2]; };

// ---------------------------------------------------------------------------
// Pack kernel (unchanged from r10). Layout [l*NPL+n][FANIN]; per-node
// bank-sort by ds_read_b64 bank-pair (idx & 15), rotated by n for near-
// uniform wave bank spread. val = (off_hi << 16) | fp16(w); off_hi = idx*8
// (pre-shifted byte offset) for tanh layers, raw idx for the final layer.
// ---------------------------------------------------------------------------
__global__ __launch_bounds__(256) void pack_edges_kernel(
    const int* __restrict__ src, const float* __restrict__ wsrc,
    unsigned int* __restrict__ packed)
{
    int t = blockIdx.x * 256 + threadIdx.x;      // one (l, n) pair per thread
    if (t >= NLAYERS * NPL) return;
    const int l = t / NPL;
    const int n = t - l * NPL;
    const int*   s  = src  + (size_t)t * FANIN;
    const float* ww = wsrc + (size_t)t * FANIN;

    int          key[FANIN];
    unsigned int val[FANIN];
#pragma unroll
    for (int f = 0; f < FANIN; ++f) {
        unsigned int idx = (unsigned int)s[f];
        key[f] = (int)(idx & 15u);
        unsigned int hi = (l < NLAYERS - 1) ? (idx << 3) : idx;
        unsigned short hw = __half_as_ushort(__float2half(ww[f]));
        val[f] = (hi << 16) | (unsigned int)hw;
    }

    unsigned int* dst = packed + (size_t)t * FANIN;
#pragma unroll
    for (int f = 0; f < FANIN; ++f) {
        int rank = 0;
#pragma unroll
        for (int g = 0; g < FANIN; ++g)
            rank += (key[g] < key[f]) || (key[g] == key[f] && g < f);
        dst[(rank - n) & 15] = val[f];
    }
}

__device__ __forceinline__ float fast_tanh(float x) {
    float t = __expf(2.0f * x);
    return 1.0f - 2.0f / (t + 1.0f);
}
__device__ __forceinline__ float fast_sigmoid(float x) {
    return 1.0f / (1.0f + __expf(-x));
}

// ---------------------------------------------------------------------------
// Fused whole-network kernel, dual-node interleaved. Each block owns 4 batch
// columns; all activations in LDS as 8-B rows [row][4 x fp16]. Per layer the
// thread's TWO nodes (tid, 1024+tid) are processed in ONE interleaved loop:
// per step f, both ds_read_b64 gathers issue together and feed 4 independent
// v_pk_fma_f16 chains -> 2x the per-wave ILP to cover LDS latency at the
// 4-waves/SIMD occupancy this LDS footprint locks us into. Next-layer pk
// prefetch issues after the gather loop (pk consumed), hiding L2 latency
// under tanh + LDS writes + barrier. One __syncthreads per layer.
// ---------------------------------------------------------------------------
__global__ __launch_bounds__(1024) void fused_net_kernel(
    const float* __restrict__ inputs,           // (BSZ, N_IN) f32
    const unsigned int* __restrict__ packed,    // [l*NPL+n][FANIN]
    const float* __restrict__ biases,           // (L, NPL) f32
    float* __restrict__ out)                    // (BSZ, N_OUT) f32
{
    extern __shared__ char lds[];
    const int tid = threadIdx.x;
    const int c0  = blockIdx.x * CPB;           // batch base for this block

    // ---- stage 4 input columns as one 8-B row record per node ----
    {
        float v0 = inputs[(size_t)(c0 + 0) * N_IN + tid];
        float v1 = inputs[(size_t)(c0 + 1) * N_IN + tid];
        float v2 = inputs[(size_t)(c0 + 2) * N_IN + tid];
        float v3 = inputs[(size_t)(c0 + 3) * N_IN + tid];
        H4 rec;
        rec.h2[0] = __halves2half2(__float2half(v0), __float2half(v1));
        rec.h2[1] = __halves2half2(__float2half(v2), __float2half(v3));
        *reinterpret_cast<unsigned long long*>(lds + (size_t)tid * ROW_B) = rec.u;
    }

    unsigned int pkA[FANIN], pkB[FANIN];

    // preload layer 0, both sweeps (overlaps with input staging + barrier)
#pragma unroll
    for (int f = 0; f < FANIN; ++f)
        pkA[f] = packed[(size_t)tid * FANIN + f];
#pragma unroll
    for (int f = 0; f < FANIN; ++f)
        pkB[f] = packed[(size_t)(1024 + tid) * FANIN + f];

    __syncthreads();

    for (int l = 0; l < NLAYERS - 1; ++l) {
        const float* bl = biases + (size_t)l * NPL;
        const int wbase = N_IN + l * NPL;

        const __half hb0 = __float2half(bl[tid]);
        const __half hb1 = __float2half(bl[1024 + tid]);
        __half2 a0_01 = __halves2half2(hb0, hb0), a0_23 = a0_01;
        __half2 a1_01 = __halves2half2(hb1, hb1), a1_23 = a1_01;

        // ---- interleaved dual-node gather + FMA (32 gathers, 4 chains) ----
#pragma unroll
        for (int f = 0; f < FANIN; ++f) {
            const unsigned int u0 = pkA[f];
            const unsigned int u1 = pkB[f];
            H4 v0, v1;
            v0.u = *reinterpret_cast<const unsigned long long*>(lds + (u0 >> 16));
            v1.u = *reinterpret_cast<const unsigned long long*>(lds + (u1 >> 16));
            const __half2 w0 = __half2half2(
                __ushort_as_half((unsigned short)(u0 & 0xffffu)));
            const __half2 w1 = __half2half2(
                __ushort_as_half((unsigned short)(u1 & 0xffffu)));
            a0_01 = __hfma2(v0.h2[0], w0, a0_01);
            a0_23 = __hfma2(v0.h2[1], w0, a0_23);
            a1_01 = __hfma2(v1.h2[0], w1, a1_01);
            a1_23 = __hfma2(v1.h2[1], w1, a1_23);
        }

        // ---- prefetch next layer's pk (pkA/pkB consumed); hides under
        //      tanh + writes + barrier ----
        if (l < NLAYERS - 2) {
#pragma unroll
            for (int f = 0; f < FANIN; ++f)
                pkA[f] = packed[((size_t)(l + 1) * NPL + tid) * FANIN + f];
#pragma unroll
            for (int f = 0; f < FANIN; ++f)
                pkB[f] = packed[((size_t)(l + 1) * NPL + 1024 + tid) * FANIN + f];
        } else if (tid < N_OUT) {
#pragma unroll
            for (int f = 0; f < FANIN; ++f)
                pkA[f] = packed[((size_t)4 * NPL + (NPL - N_OUT) + tid) * FANIN + f];
        }

        // ---- activations + LDS row writes ----
        {
            float t0 = fast_tanh(__half2float(__low2half(a0_01)));
            float t1 = fast_tanh(__half2float(__high2half(a0_01)));
            float t2 = fast_tanh(__half2float(__low2half(a0_23)));
            float t3 = fast_tanh(__half2float(__high2half(a0_23)));
            H4 rec;
            rec.h2[0] = __halves2half2(__float2half(t0), __float2half(t1));
            rec.h2[1] = __halves2half2(__float2half(t2), __float2half(t3));
            *reinterpret_cast<unsigned long long*>(
                lds + (size_t)(wbase + tid) * ROW_B) = rec.u;
        }
        {
            float t0 = fast_tanh(__half2float(__low2half(a1_01)));
            float t1 = fast_tanh(__half2float(__high2half(a1_01)));
            float t2 = fast_tanh(__half2float(__low2half(a1_23)));
            float t3 = fast_tanh(__half2float(__high2half(a1_23)));
            H4 rec;
            rec.h2[0] = __halves2half2(__float2half(t0), __float2half(t1));
            rec.h2[1] = __halves2half2(__float2half(t2), __float2half(t3));
            *reinterpret_cast<unsigned long long*>(
                lds + (size_t)(wbase + 1024 + tid) * ROW_B) = rec.u;
        }
        __syncthreads();
    }

    // ---- layer 4: last N_OUT nodes only; f32 accum; sigmoid; f32 out ----
    if (tid < N_OUT) {
        const float bv = biases[(size_t)4 * NPL + (NPL - N_OUT) + tid];
        float a0 = bv, a1 = bv, a2 = bv, a3 = bv;
#pragma unroll
        for (int f = 0; f < FANIN; ++f) {
            const unsigned int u   = pkA[f];
            const unsigned int off = (u >> 16) << 3;     // raw idx -> byte off
            H4 v;
            v.u = *reinterpret_cast<const unsigned long long*>(lds + off);
            const float wf = __half2float(
                __ushort_as_half((unsigned short)(u & 0xffffu)));
            a0 = fmaf(__half2float(v.h2[0].x), wf, a0);
            a1 = fmaf(__half2float(v.h2[0].y), wf, a1);
            a2 = fmaf(__half2float(v.h2[1].x), wf, a2);
            a3 = fmaf(__half2float(v.h2[1].y), wf, a3);
        }
        a0 = fast_sigmoid(a0); a1 = fast_sigmoid(a1);
        a2 = fast_sigmoid(a2); a3 = fast_sigmoid(a3);
        const int j = tid;                               // output column
        out[(size_t)(c0 + 0) * N_OUT + j] = a0;
        out[(size_t)(c0 + 1) * N_OUT + j] = a1;
        out[(size_t)(c0 + 2) * N_OUT + j] = a2;
        out[(size_t)(c0 + 3) * N_OUT + j] = a3;
    }
}

// ---------------------------------------------------------------------------
// Launch: pack edges into d_ws (0.66 MB), then one fused kernel.
// 256 blocks x 1024 threads, 73728 B dynamic LDS per block.
// ---------------------------------------------------------------------------
extern "C" void kernel_launch(void* const* d_in, const int* in_sizes, int n_in,
                              void* d_out, int out_size, void* d_ws, size_t ws_size,
                              hipStream_t stream)
{
    const float* inputs   = (const float*)d_in[0];
    const int*   edge_src = (const int*)  d_in[1];
    const float* edge_w   = (const float*)d_in[2];
    const float* biases   = (const float*)d_in[3];
    float* out = (float*)d_out;
    unsigned int* packed = (unsigned int*)d_ws;   // L*NPL*FANIN*4 B = 655,360 B

    pack_edges_kernel<<<(NLAYERS * NPL + 255) / 256, 256, 0, stream>>>(
        edge_src, edge_w, packed);

    fused_net_kernel<<<NBLK, 1024, LDS_BYTES, stream>>>(
        inputs, packed, biases, out);
}